// Round 5
// baseline (2911.000 us; speedup 1.0000x reference)
//
#include <hip/hip_runtime.h>
#include <stdint.h>

#define N_ROWS 4096
#define DIM    512
#define VOCAB  50000
#define VPAD   50048
#define TOPK   10
#define MARGIN 8.0f            // i8 band: >=13 sigma of quantization error
#define MAXU   32              // per-row uncertain-list capacity (expected ~13)
#define ECHUNKS 196            // full-scan chunks (overflow safety net only)

typedef int   i32x4 __attribute__((ext_vector_type(4)));

#define GLOBAL_AS __attribute__((address_space(1)))
#define LDS_AS    __attribute__((address_space(3)))

// ---------------- per-row int8 quantization ----------------
__device__ __forceinline__ void quant_row(const float* __restrict__ src,
                                          signed char* __restrict__ dst,
                                          int lane, float* rowmax_out,
                                          float* w2_out) {
    const float4* s4 = (const float4*)(src + lane * 8);
    float4 a = s4[0], b = s4[1];
    float mx = fmaxf(fmaxf(fmaxf(fabsf(a.x), fabsf(a.y)), fmaxf(fabsf(a.z), fabsf(a.w))),
                     fmaxf(fmaxf(fabsf(b.x), fabsf(b.y)), fmaxf(fabsf(b.z), fabsf(b.w))));
    float w2 = a.x*a.x + a.y*a.y + a.z*a.z + a.w*a.w
             + b.x*b.x + b.y*b.y + b.z*b.z + b.w*b.w;
    #pragma unroll
    for (int off = 1; off < 64; off <<= 1) {
        mx  = fmaxf(mx, __shfl_xor(mx, off, 64));
        w2 += __shfl_xor(w2, off, 64);
    }
    float inv = 127.0f / fmaxf(mx, 1e-30f);
    int q0 = (int)rintf(a.x * inv), q1 = (int)rintf(a.y * inv);
    int q2 = (int)rintf(a.z * inv), q3 = (int)rintf(a.w * inv);
    int q4 = (int)rintf(b.x * inv), q5 = (int)rintf(b.y * inv);
    int q6 = (int)rintf(b.z * inv), q7 = (int)rintf(b.w * inv);
    uint2 pk;
    pk.x = (q0 & 0xff) | ((q1 & 0xff) << 8) | ((q2 & 0xff) << 16) | ((unsigned)(q3 & 0xff) << 24);
    pk.y = (q4 & 0xff) | ((q5 & 0xff) << 8) | ((q6 & 0xff) << 16) | ((unsigned)(q7 & 0xff) << 24);
    *(uint2*)(dst + lane * 8) = pk;
    *rowmax_out = mx;
    *w2_out = w2;
}

__global__ __launch_bounds__(256) void quantize_x(const float* __restrict__ X,
                                                  signed char* __restrict__ Xq,
                                                  float* __restrict__ sx) {
    int wave = threadIdx.x >> 6, lane = threadIdx.x & 63;
    int row = blockIdx.x * 4 + wave;
    float mx, w2;
    quant_row(X + (size_t)row * DIM, Xq + (size_t)row * DIM, lane, &mx, &w2);
    if (lane == 0) sx[row] = fmaxf(mx, 1e-30f) / 127.0f;
}

__global__ __launch_bounds__(256) void quantize_w(const float* __restrict__ W,
                                                  signed char* __restrict__ Wq,
                                                  float* __restrict__ sw,
                                                  float* __restrict__ w2) {
    int wave = threadIdx.x >> 6, lane = threadIdx.x & 63;
    int row = blockIdx.x * 4 + wave;
    if (row < VOCAB) {
        float mx, s2;
        quant_row(W + (size_t)row * DIM, Wq + (size_t)row * DIM, lane, &mx, &s2);
        if (lane == 0) { sw[row] = fmaxf(mx, 1e-30f) / 127.0f; w2[row] = s2; }
    } else {
        *(uint2*)(Wq + (size_t)row * DIM + lane * 8) = make_uint2(0, 0);
        if (lane == 0) { sw[row] = 0.0f; w2[row] = 1e30f; }
    }
}

// ---------- st[n] = ||w_t||^2 - 2 x_n . w_t (fp32 exact) ----------
__global__ __launch_bounds__(64) void st_kernel(const float* __restrict__ X,
                                                const float* __restrict__ W,
                                                const int* __restrict__ target,
                                                float* __restrict__ st) {
    int n = blockIdx.x;
    int t = target[n];
    const float4* x4 = (const float4*)(X + (size_t)n * DIM);
    const float4* w4 = (const float4*)(W + (size_t)t * DIM);
    int lane = threadIdx.x;
    float4 xa = x4[lane], xb = x4[lane + 64];
    float4 wa = w4[lane], wb = w4[lane + 64];
    float sxw = xa.x*wa.x + xa.y*wa.y + xa.z*wa.z + xa.w*wa.w
              + xb.x*wb.x + xb.y*wb.y + xb.z*wb.z + xb.w*wb.w;
    float sww = wa.x*wa.x + wa.y*wa.y + wa.z*wa.z + wa.w*wa.w
              + wb.x*wb.x + wb.y*wb.y + wb.z*wb.z + wb.w*wb.w;
    #pragma unroll
    for (int off = 32; off > 0; off >>= 1) {
        sxw += __shfl_down(sxw, off, 64);
        sww += __shfl_down(sww, off, 64);
    }
    if (lane == 0) st[n] = sww - 2.0f * sxw;
}

// ---------------- i8 MFMA GEMM + band-count + uncertain-list ----------------
// 128x128 tile, BK=128 bytes (4 k-iters), 4 waves (2x2), mfma_i32_16x16x64_i8.
// LDS rows are 128 B with XOR-3 chunk swizzle: LDS[r][cs] = G[r][cs ^ (r&7)]
// (staging permutes the GLOBAL source per lane; glds dest stays lane-contiguous).
__global__ __launch_bounds__(256) void count_mfma_i8(
        const signed char* __restrict__ Xq, const signed char* __restrict__ Wq,
        const float* __restrict__ sx, const float* __restrict__ sw,
        const float* __restrict__ w2, const float* __restrict__ st,
        const int* __restrict__ target,
        int* __restrict__ cnt_def, int* __restrict__ uncn,
        unsigned int* __restrict__ unc_list) {

    __shared__ signed char Als[128 * 128];
    __shared__ signed char Bls[128 * 128];
    __shared__ float w2_s[128];
    __shared__ float sw_s[128];
    __shared__ float st_s[128];
    __shared__ float sx_s[128];
    __shared__ int   t_s[128];
    __shared__ int   pk_s[128];

    const int tid  = threadIdx.x;
    const int wave = tid >> 6, lane = tid & 63;
    const int row0 = blockIdx.x * 128;          // x fastest -> W-tile reuse across 32 blocks
    const int col0 = blockIdx.y * 128;

    if (tid < 128) { w2_s[tid] = w2[col0 + tid]; sw_s[tid] = sw[col0 + tid]; pk_s[tid] = 0; }
    else           { st_s[tid - 128] = st[row0 + tid - 128];
                     sx_s[tid - 128] = sx[row0 + tid - 128];
                     t_s[tid - 128]  = target[row0 + tid - 128]; }

    // staging: each wave stages 32 rows of A and of B per k-iter.
    // One glds: 64 lanes x 16 B = 8 rows of 128 B. lane -> (row=lane>>3, chunk=lane&7),
    // fetching global chunk (lane&7) ^ (row&7) so swizzled LDS holds G[r][cs^(r&7)].
    const int r8 = lane >> 3;                    // row within 8-row group
    const int ch = (lane & 7) ^ (r8 & 7);        // swizzled global chunk
    const signed char* ga = Xq + (size_t)(row0 + wave*32 + r8) * DIM + ch * 16;
    const signed char* gb = Wq + (size_t)(col0 + wave*32 + r8) * DIM + ch * 16;
    signed char* la = &Als[(wave*32) * 128];
    signed char* lb = &Bls[(wave*32) * 128];

    const int q = lane >> 4, c = lane & 15;      // quad, col-in-16
    const int cl = c & 7;
    const int wm = wave >> 1, wn = wave & 1;
    // frag read ptrs: row part (wm*64 + i*16 + c)*128; chunk = (sub*4+q) ^ (c&7)
    const signed char* ap0 = &Als[(wm*64 + c) * 128 + ((q    ) ^ cl) * 16];
    const signed char* ap1 = &Als[(wm*64 + c) * 128 + ((q + 4) ^ cl) * 16];
    const signed char* bp0 = &Bls[(wn*64 + c) * 128 + ((q    ) ^ cl) * 16];
    const signed char* bp1 = &Bls[(wn*64 + c) * 128 + ((q + 4) ^ cl) * 16];

    i32x4 acc[4][4];
    #pragma unroll
    for (int i = 0; i < 4; i++)
        #pragma unroll
        for (int j = 0; j < 4; j++) acc[i][j] = (i32x4){0, 0, 0, 0};

    for (int k0 = 0; k0 < DIM; k0 += 128) {
        #pragma unroll
        for (int g = 0; g < 4; g++) {
            __builtin_amdgcn_global_load_lds((const GLOBAL_AS void*)(ga + (size_t)g*8*DIM + k0),
                                             (LDS_AS void*)(la + g*8*128), 16, 0, 0);
            __builtin_amdgcn_global_load_lds((const GLOBAL_AS void*)(gb + (size_t)g*8*DIM + k0),
                                             (LDS_AS void*)(lb + g*8*128), 16, 0, 0);
        }
        __syncthreads();
        i32x4 af0[4], bf0[4], af1[4], bf1[4];
        #pragma unroll
        for (int i = 0; i < 4; i++) {
            af0[i] = *(const i32x4*)(ap0 + i * 16 * 128);
            af1[i] = *(const i32x4*)(ap1 + i * 16 * 128);
        }
        #pragma unroll
        for (int j = 0; j < 4; j++) {
            bf0[j] = *(const i32x4*)(bp0 + j * 16 * 128);
            bf1[j] = *(const i32x4*)(bp1 + j * 16 * 128);
        }
        #pragma unroll
        for (int i = 0; i < 4; i++)
            #pragma unroll
            for (int j = 0; j < 4; j++)
                acc[i][j] = __builtin_amdgcn_mfma_i32_16x16x64_i8(af0[i], bf0[j], acc[i][j], 0, 0, 0);
        #pragma unroll
        for (int i = 0; i < 4; i++)
            #pragma unroll
            for (int j = 0; j < 4; j++)
                acc[i][j] = __builtin_amdgcn_mfma_i32_16x16x64_i8(af1[i], bf1[j], acc[i][j], 0, 0, 0);
        __syncthreads();
    }

    // epilogue: banded compare-count. C/D: col=lane&15, row=q*4+reg (dtype-independent).
    #pragma unroll
    for (int i = 0; i < 4; i++) {
        #pragma unroll
        for (int reg = 0; reg < 4; reg++) {
            int r = wm*64 + i*16 + q*4 + reg;
            float stv = st_s[r];
            float sxr = sx_s[r];
            int   t   = t_s[r];
            int def = 0;
            #pragma unroll
            for (int j = 0; j < 4; j++) {
                int col_l = wn*64 + j*16 + c;
                float dot = sxr * sw_s[col_l] * (float)acc[i][j][reg];
                float s = w2_s[col_l] - 2.0f * dot;
                int v = col0 + col_l;                 // pad cols: w2=1e30 -> never counted
                if (v != t) {
                    if (s < stv - MARGIN) def++;
                    else if (s < stv + MARGIN) {
                        int pos = atomicAdd(&uncn[row0 + r], 1);
                        if (pos < MAXU)
                            unc_list[(size_t)(row0 + r) * MAXU + pos] = (unsigned)v;
                    }
                }
            }
            def += __shfl_xor(def, 1, 64);
            def += __shfl_xor(def, 2, 64);
            def += __shfl_xor(def, 4, 64);
            def += __shfl_xor(def, 8, 64);
            if (c == 0 && def) atomicAdd(&pk_s[r], def);
        }
    }
    __syncthreads();
    if (tid < 128) {
        int d = pk_s[tid];
        if (d) atomicAdd(&cnt_def[row0 + tid], d);
    }
}

// ---------------- resolve ----------------
// hit: 0=miss, 1=hit, 2=ambiguous via pairs list, 3=ambiguous overflow (full scan)
__global__ __launch_bounds__(256) void resolve_kernel(const int* __restrict__ cnt_def,
                                                      const int* __restrict__ uncn,
                                                      const unsigned int* __restrict__ unc_list,
                                                      int* __restrict__ hit,
                                                      int* __restrict__ count_exact,
                                                      unsigned int* __restrict__ pairs,
                                                      int* __restrict__ pair_count,
                                                      int* __restrict__ amb_rows,
                                                      int* __restrict__ amb_count) {
    int n = blockIdx.x * 256 + threadIdx.x;
    if (n >= N_ROWS) return;
    int d = cnt_def[n], u = uncn[n];
    int h;
    if (d >= TOPK) h = 0;
    else if (d + u < TOPK) h = 1;
    else if (u <= MAXU) {
        h = 2;
        count_exact[n] = d;
        int base = atomicAdd(pair_count, u);
        for (int k = 0; k < u; k++)
            pairs[base + k] = ((unsigned)n << 16) | unc_list[(size_t)n * MAXU + k];
    } else {
        h = 3;
        int idx = atomicAdd(amb_count, 1);
        amb_rows[idx] = n;
    }
    hit[n] = h;
}

// ---------------- exact fp32 check of uncertain pairs (wave per pair) ----------------
__global__ __launch_bounds__(256) void exact_pairs(const float* __restrict__ X,
                                                   const float* __restrict__ W,
                                                   const float* __restrict__ w2,
                                                   const float* __restrict__ st,
                                                   const int* __restrict__ target,
                                                   const unsigned int* __restrict__ pairs,
                                                   const int* __restrict__ pair_count,
                                                   int* __restrict__ count_exact) {
    const int wave = threadIdx.x >> 6, lane = threadIdx.x & 63;
    const int np = pair_count[0];
    for (int p = blockIdx.x * 4 + wave; p < np; p += gridDim.x * 4) {
        unsigned pk = pairs[p];
        int row = pk >> 16, v = pk & 0xffff;
        const float4* xr = (const float4*)(X + (size_t)row * DIM + lane * 8);
        const float4* wr = (const float4*)(W + (size_t)v   * DIM + lane * 8);
        float4 xa = xr[0], xb = xr[1];
        float4 wa = wr[0], wb = wr[1];
        float pdot = xa.x*wa.x + xa.y*wa.y + xa.z*wa.z + xa.w*wa.w
                   + xb.x*wb.x + xb.y*wb.y + xb.z*wb.z + xb.w*wb.w;
        pdot += __shfl_xor(pdot, 1, 64);
        pdot += __shfl_xor(pdot, 2, 64);
        pdot += __shfl_xor(pdot, 4, 64);
        pdot += __shfl_xor(pdot, 8, 64);
        pdot += __shfl_xor(pdot, 16, 64);
        pdot += __shfl_xor(pdot, 32, 64);
        if (lane == 0) {
            float s = w2[v] - 2.0f * pdot;
            float stv = st[row];
            int t = target[row];
            if (s < stv || (s == stv && v < t)) atomicAdd(&count_exact[row], 1);
        }
    }
}

// ---------------- full exact rescan (overflow rows only; normally 0) ----------------
__global__ __launch_bounds__(256) void exact_kernel(const float* __restrict__ X,
                                                    const float* __restrict__ W,
                                                    const float* __restrict__ w2,
                                                    const float* __restrict__ st,
                                                    const int* __restrict__ target,
                                                    const int* __restrict__ amb_rows,
                                                    const int* __restrict__ amb_count,
                                                    int* __restrict__ count_exact) {
    __shared__ float xs[DIM];
    __shared__ int scnt[4];
    const int tid = threadIdx.x, wave = tid >> 6, lane = tid & 63;
    const int nw = amb_count[0] * ECHUNKS;
    for (int w = blockIdx.x; w < nw; w += gridDim.x) {
        const int row   = amb_rows[w / ECHUNKS];
        const int chunk = w % ECHUNKS;
        __syncthreads();
        for (int i = tid; i < DIM; i += 256) xs[i] = X[(size_t)row * DIM + i];
        if (tid < 4) scnt[tid] = 0;
        __syncthreads();
        const float4 xa = *(const float4*)&xs[lane * 8];
        const float4 xb = *(const float4*)&xs[lane * 8 + 4];
        const float stv = st[row];
        const int   t   = target[row];
        int cnt = 0;
        const int v0 = chunk * 256 + wave * 64;
        #pragma unroll 2
        for (int i = 0; i < 64; i++) {
            int v = v0 + i;
            if (v < VOCAB) {
                const float4* wr = (const float4*)(W + (size_t)v * DIM + lane * 8);
                float4 wa = wr[0], wb = wr[1];
                float p = xa.x*wa.x + xa.y*wa.y + xa.z*wa.z + xa.w*wa.w
                        + xb.x*wb.x + xb.y*wb.y + xb.z*wb.z + xb.w*wb.w;
                p += __shfl_xor(p, 1, 64);
                p += __shfl_xor(p, 2, 64);
                p += __shfl_xor(p, 4, 64);
                p += __shfl_xor(p, 8, 64);
                p += __shfl_xor(p, 16, 64);
                p += __shfl_xor(p, 32, 64);
                float s = w2[v] - 2.0f * p;
                if (lane == 0 && v != t && (s < stv || (s == stv && v < t))) cnt++;
            }
        }
        if (lane == 0) scnt[wave] = cnt;
        __syncthreads();
        if (tid == 0)
            atomicAdd(&count_exact[row], scnt[0] + scnt[1] + scnt[2] + scnt[3]);
    }
}

// ---------------- final reduction ----------------
__global__ __launch_bounds__(256) void finalize2(const int* __restrict__ hit,
                                                 const int* __restrict__ count_exact,
                                                 const int* __restrict__ mask,
                                                 float* __restrict__ out) {
    int tid = threadIdx.x;
    int hits = 0, msum = 0;
    for (int n = tid; n < N_ROWS; n += 256) {
        int m = mask[n];
        msum += m;
        int h = hit[n];
        int hv = (h >= 2) ? (count_exact[n] < TOPK ? 1 : 0) : h;
        if (m) hits += hv;
    }
    #pragma unroll
    for (int off = 32; off > 0; off >>= 1) {
        hits += __shfl_down(hits, off, 64);
        msum += __shfl_down(msum, off, 64);
    }
    __shared__ int sh[8];
    int wid = tid >> 6, lane = tid & 63;
    if (lane == 0) { sh[wid] = hits; sh[4 + wid] = msum; }
    __syncthreads();
    if (tid == 0) {
        int H = sh[0] + sh[1] + sh[2] + sh[3];
        int M = sh[4] + sh[5] + sh[6] + sh[7];
        out[0] = (float)H / (float)M;
    }
}

// ================= round-1 verified fp32 fallback (if ws too small) =================
#define BM 128
#define BN 128
#define BK 16
#define TM 8
#define TN 8

__global__ __launch_bounds__(64) void w2_kernel_fb(const float* __restrict__ W,
                                                   float* __restrict__ w2) {
    int v = blockIdx.x;
    const float4* w4 = (const float4*)(W + (size_t)v * DIM);
    int lane = threadIdx.x;
    float4 a = w4[lane];
    float4 b = w4[lane + 64];
    float s = a.x*a.x + a.y*a.y + a.z*a.z + a.w*a.w
            + b.x*b.x + b.y*b.y + b.z*b.z + b.w*b.w;
    #pragma unroll
    for (int off = 32; off > 0; off >>= 1) s += __shfl_down(s, off, 64);
    if (lane == 0) w2[v] = s;
}

__global__ __launch_bounds__(256) void count_kernel_fb(
        const float* __restrict__ X, const float* __restrict__ W,
        const float* __restrict__ w2, const float* __restrict__ st,
        const int* __restrict__ target, int* __restrict__ count) {
    __shared__ float Xs[BK][BM];
    __shared__ float Ws[BK][BN];
    __shared__ float st_s[BM];
    __shared__ int   t_s[BM];
    __shared__ float w2_s[BN];
    const int tid  = threadIdx.x;
    const int row0 = blockIdx.y * BM;
    const int col0 = blockIdx.x * BN;
    if (tid < 128) { st_s[tid] = st[row0 + tid]; t_s[tid] = target[row0 + tid]; }
    else { int cc = tid - 128; int v = col0 + cc; if (v >= VOCAB) v = VOCAB - 1; w2_s[cc] = w2[v]; }
    float acc[TM][TN] = {};
    const int tx = tid & 15;
    const int ty = tid >> 4;
    for (int k0 = 0; k0 < DIM; k0 += BK) {
        #pragma unroll
        for (int j = 0; j < 2; j++) {
            int idx = tid + 256 * j;
            int r   = idx >> 2;
            int kq  = idx & 3;
            float4 xv = *(const float4*)(X + (size_t)(row0 + r) * DIM + k0 + kq * 4);
            Xs[kq*4+0][r] = xv.x; Xs[kq*4+1][r] = xv.y;
            Xs[kq*4+2][r] = xv.z; Xs[kq*4+3][r] = xv.w;
            int v = col0 + r; if (v >= VOCAB) v = VOCAB - 1;
            float4 wv = *(const float4*)(W + (size_t)v * DIM + k0 + kq * 4);
            Ws[kq*4+0][r] = wv.x; Ws[kq*4+1][r] = wv.y;
            Ws[kq*4+2][r] = wv.z; Ws[kq*4+3][r] = wv.w;
        }
        __syncthreads();
        #pragma unroll
        for (int kk = 0; kk < BK; kk++) {
            float a[TM], b[TN];
            #pragma unroll
            for (int i = 0; i < TM; i++) a[i] = Xs[kk][ty * TM + i];
            #pragma unroll
            for (int j = 0; j < TN; j++) b[j] = Ws[kk][tx * TN + j];
            #pragma unroll
            for (int i = 0; i < TM; i++)
                #pragma unroll
                for (int j = 0; j < TN; j++)
                    acc[i][j] += a[i] * b[j];
        }
        __syncthreads();
    }
    int cnt[TM];
    #pragma unroll
    for (int i = 0; i < TM; i++) {
        cnt[i] = 0;
        float stv = st_s[ty * TM + i];
        int   t   = t_s[ty * TM + i];
        #pragma unroll
        for (int j = 0; j < TN; j++) {
            int v = col0 + tx * TN + j;
            float s = w2_s[tx * TN + j] - 2.0f * acc[i][j];
            if (v < VOCAB && v != t && (s < stv || (s == stv && v < t))) cnt[i]++;
        }
    }
    __syncthreads();
    int* scnt = (int*)Xs;
    #pragma unroll
    for (int i = 0; i < TM; i++) scnt[(ty * TM + i) * 16 + tx] = cnt[i];
    __syncthreads();
    if (tid < BM) {
        int s = 0;
        #pragma unroll
        for (int j = 0; j < 16; j++) s += scnt[tid * 16 + j];
        atomicAdd(&count[row0 + tid], s);
    }
}

__global__ __launch_bounds__(256) void finalize_fb(const int* __restrict__ count,
                                                   const int* __restrict__ mask,
                                                   float* __restrict__ out) {
    int tid = threadIdx.x;
    int hits = 0, msum = 0;
    for (int n = tid; n < N_ROWS; n += 256) {
        int m = mask[n];
        msum += m;
        if (m && count[n] < TOPK) hits++;
    }
    #pragma unroll
    for (int off = 32; off > 0; off >>= 1) {
        hits += __shfl_down(hits, off, 64);
        msum += __shfl_down(msum, off, 64);
    }
    __shared__ int sh[8];
    int wid = tid >> 6, lane = tid & 63;
    if (lane == 0) { sh[wid] = hits; sh[4 + wid] = msum; }
    __syncthreads();
    if (tid == 0) {
        int H = sh[0] + sh[1] + sh[2] + sh[3];
        int M = sh[4] + sh[5] + sh[6] + sh[7];
        out[0] = (float)H / (float)M;
    }
}

// ================= launch =================
extern "C" void kernel_launch(void* const* d_in, const int* in_sizes, int n_in,
                              void* d_out, int out_size, void* d_ws, size_t ws_size,
                              hipStream_t stream) {
    const float* X      = (const float*)d_in[0];
    const int*   target = (const int*)d_in[1];
    const int*   mask   = (const int*)d_in[2];
    const float* W      = (const float*)d_in[3];
    float* out = (float*)d_out;
    char* ws = (char*)d_ws;

    const size_t oXq   = 0;
    const size_t oWq   = oXq  + (size_t)N_ROWS * DIM;       //  2,097,152
    const size_t osx   = oWq  + (size_t)VPAD  * DIM;        // 27,721,728
    const size_t osw   = osx  + (size_t)N_ROWS * 4;
    const size_t ow2   = osw  + (size_t)VPAD * 4;
    const size_t ost   = ow2  + (size_t)VPAD * 4;
    const size_t ocd   = ost  + (size_t)N_ROWS * 4;         // zeroed from here:
    const size_t oun   = ocd  + (size_t)N_ROWS * 4;
    const size_t oce   = oun  + (size_t)N_ROWS * 4;
    const size_t ohit  = oce  + (size_t)N_ROWS * 4;
    const size_t oamb  = ohit + (size_t)N_ROWS * 4;
    const size_t oambc = oamb + (size_t)N_ROWS * 4;
    const size_t opc   = oambc + 16;
    const size_t ounl  = opc  + 16;                          // unc_list 4096*32*4 = 512K
    const size_t oprs  = ounl + (size_t)N_ROWS * MAXU * 4;   // pairs 512K
    const size_t need  = oprs + (size_t)N_ROWS * MAXU * 4;

    if (ws_size >= need) {
        signed char* Xq = (signed char*)(ws + oXq);
        signed char* Wq = (signed char*)(ws + oWq);
        float* sx = (float*)(ws + osx);
        float* sw = (float*)(ws + osw);
        float* w2 = (float*)(ws + ow2);
        float* st = (float*)(ws + ost);
        int* cnt_def = (int*)(ws + ocd);
        int* uncn = (int*)(ws + oun);
        int* count_exact = (int*)(ws + oce);
        int* hit = (int*)(ws + ohit);
        int* amb_rows = (int*)(ws + oamb);
        int* amb_count = (int*)(ws + oambc);
        int* pair_count = (int*)(ws + opc);
        unsigned int* unc_list = (unsigned int*)(ws + ounl);
        unsigned int* pairs = (unsigned int*)(ws + oprs);

        hipMemsetAsync(ws + ocd, 0, opc + 16 - ocd, stream);  // cnt_def..pair_count
        quantize_x<<<N_ROWS / 4, 256, 0, stream>>>(X, Xq, sx);
        quantize_w<<<VPAD / 4, 256, 0, stream>>>(W, Wq, sw, w2);
        st_kernel<<<N_ROWS, 64, 0, stream>>>(X, W, target, st);
        count_mfma_i8<<<dim3(N_ROWS / 128, VPAD / 128), 256, 0, stream>>>(
            Xq, Wq, sx, sw, w2, st, target, cnt_def, uncn, unc_list);
        resolve_kernel<<<16, 256, 0, stream>>>(cnt_def, uncn, unc_list, hit,
                                               count_exact, pairs, pair_count,
                                               amb_rows, amb_count);
        exact_pairs<<<128, 256, 0, stream>>>(X, W, w2, st, target, pairs, pair_count, count_exact);
        exact_kernel<<<512, 256, 0, stream>>>(X, W, w2, st, target, amb_rows, amb_count, count_exact);
        finalize2<<<1, 256, 0, stream>>>(hit, count_exact, mask, out);
    } else {
        float* w2 = (float*)ws;
        float* st = (float*)(ws + 200704);
        int* countp = (int*)(ws + 200704 + 16384);
        hipMemsetAsync(countp, 0, N_ROWS * sizeof(int), stream);
        w2_kernel_fb<<<VOCAB, 64, 0, stream>>>(W, w2);
        st_kernel<<<N_ROWS, 64, 0, stream>>>(X, W, target, st);
        dim3 grid((VOCAB + BN - 1) / BN, N_ROWS / BM);
        count_kernel_fb<<<grid, 256, 0, stream>>>(X, W, w2, st, target, countp);
        finalize_fb<<<1, 256, 0, stream>>>(countp, mask, out);
    }
}

// Round 6
// 453.646 us; speedup vs baseline: 6.4169x; 6.4169x over previous
//
#include <hip/hip_runtime.h>
#include <stdint.h>

#define N_ROWS 4096
#define DIM    512
#define VOCAB  50000
#define VPAD   50048
#define TOPK   10
#define MARGIN 8.0f            // i8 band: >=13 sigma of quantization error
#define MAXB   64              // per-row band capacity before full-scan fallback
#define ECHUNKS 196            // full-scan chunks (overflow safety net only)

typedef int   i32x4 __attribute__((ext_vector_type(4)));

#define GLOBAL_AS __attribute__((address_space(1)))
#define LDS_AS    __attribute__((address_space(3)))

// ---------------- per-row int8 quantization ----------------
__device__ __forceinline__ void quant_row(const float* __restrict__ src,
                                          signed char* __restrict__ dst,
                                          int lane, float* rowmax_out,
                                          float* w2_out) {
    const float4* s4 = (const float4*)(src + lane * 8);
    float4 a = s4[0], b = s4[1];
    float mx = fmaxf(fmaxf(fmaxf(fabsf(a.x), fabsf(a.y)), fmaxf(fabsf(a.z), fabsf(a.w))),
                     fmaxf(fmaxf(fabsf(b.x), fabsf(b.y)), fmaxf(fabsf(b.z), fabsf(b.w))));
    float w2 = a.x*a.x + a.y*a.y + a.z*a.z + a.w*a.w
             + b.x*b.x + b.y*b.y + b.z*b.z + b.w*b.w;
    #pragma unroll
    for (int off = 1; off < 64; off <<= 1) {
        mx  = fmaxf(mx, __shfl_xor(mx, off, 64));
        w2 += __shfl_xor(w2, off, 64);
    }
    float inv = 127.0f / fmaxf(mx, 1e-30f);
    int q0 = (int)rintf(a.x * inv), q1 = (int)rintf(a.y * inv);
    int q2 = (int)rintf(a.z * inv), q3 = (int)rintf(a.w * inv);
    int q4 = (int)rintf(b.x * inv), q5 = (int)rintf(b.y * inv);
    int q6 = (int)rintf(b.z * inv), q7 = (int)rintf(b.w * inv);
    uint2 pk;
    pk.x = (q0 & 0xff) | ((q1 & 0xff) << 8) | ((q2 & 0xff) << 16) | ((unsigned)(q3 & 0xff) << 24);
    pk.y = (q4 & 0xff) | ((q5 & 0xff) << 8) | ((q6 & 0xff) << 16) | ((unsigned)(q7 & 0xff) << 24);
    *(uint2*)(dst + lane * 8) = pk;
    *rowmax_out = mx;
    *w2_out = w2;
}

__global__ __launch_bounds__(256) void quantize_x(const float* __restrict__ X,
                                                  signed char* __restrict__ Xq,
                                                  float* __restrict__ sx) {
    int wave = threadIdx.x >> 6, lane = threadIdx.x & 63;
    int row = blockIdx.x * 4 + wave;
    float mx, w2;
    quant_row(X + (size_t)row * DIM, Xq + (size_t)row * DIM, lane, &mx, &w2);
    if (lane == 0) sx[row] = fmaxf(mx, 1e-30f) / 127.0f;
}

__global__ __launch_bounds__(256) void quantize_w(const float* __restrict__ W,
                                                  signed char* __restrict__ Wq,
                                                  float* __restrict__ sw,
                                                  float* __restrict__ w2) {
    int wave = threadIdx.x >> 6, lane = threadIdx.x & 63;
    int row = blockIdx.x * 4 + wave;
    if (row < VOCAB) {
        float mx, s2;
        quant_row(W + (size_t)row * DIM, Wq + (size_t)row * DIM, lane, &mx, &s2);
        if (lane == 0) { sw[row] = fmaxf(mx, 1e-30f) / 127.0f; w2[row] = s2; }
    } else {
        *(uint2*)(Wq + (size_t)row * DIM + lane * 8) = make_uint2(0, 0);
        if (lane == 0) { sw[row] = 0.0f; w2[row] = 1e30f; }
    }
}

// ---------- st[n] = ||w_t||^2 - 2 x_n . w_t (fp32 exact) ----------
__global__ __launch_bounds__(64) void st_kernel(const float* __restrict__ X,
                                                const float* __restrict__ W,
                                                const int* __restrict__ target,
                                                float* __restrict__ st) {
    int n = blockIdx.x;
    int t = target[n];
    const float4* x4 = (const float4*)(X + (size_t)n * DIM);
    const float4* w4 = (const float4*)(W + (size_t)t * DIM);
    int lane = threadIdx.x;
    float4 xa = x4[lane], xb = x4[lane + 64];
    float4 wa = w4[lane], wb = w4[lane + 64];
    float sxw = xa.x*wa.x + xa.y*wa.y + xa.z*wa.z + xa.w*wa.w
              + xb.x*wb.x + xb.y*wb.y + xb.z*wb.z + xb.w*wb.w;
    float sww = wa.x*wa.x + wa.y*wa.y + wa.z*wa.z + wa.w*wa.w
              + wb.x*wb.x + wb.y*wb.y + wb.z*wb.z + wb.w*wb.w;
    #pragma unroll
    for (int off = 32; off > 0; off >>= 1) {
        sxw += __shfl_down(sxw, off, 64);
        sww += __shfl_down(sww, off, 64);
    }
    if (lane == 0) st[n] = sww - 2.0f * sxw;
}

// ---------------- i8 MFMA GEMM + band-count (round-4 verified, verbatim) ----------------
// 128x128 tile, BK=64 (bytes), 4 waves (2x2), mfma_i32_16x16x64_i8, 4x4 frags/wave.
__global__ __launch_bounds__(256) void count_mfma_i8(
        const signed char* __restrict__ Xq, const signed char* __restrict__ Wq,
        const float* __restrict__ sx, const float* __restrict__ sw,
        const float* __restrict__ w2, const float* __restrict__ st,
        const int* __restrict__ target,
        int* __restrict__ cnt_def, int* __restrict__ cnt_unc) {

    __shared__ signed char Als[128 * 64];
    __shared__ signed char Bls[128 * 64];
    __shared__ float w2_s[128];
    __shared__ float sw_s[128];
    __shared__ float st_s[128];
    __shared__ float sx_s[128];
    __shared__ int   t_s[128];
    __shared__ int   pk_s[128];

    const int tid  = threadIdx.x;
    const int wave = tid >> 6, lane = tid & 63;
    const int row0 = blockIdx.x * 128;          // x fastest -> W-tile reuse across 32 blocks
    const int col0 = blockIdx.y * 128;

    if (tid < 128) { w2_s[tid] = w2[col0 + tid]; sw_s[tid] = sw[col0 + tid]; pk_s[tid] = 0; }
    else           { st_s[tid - 128] = st[row0 + tid - 128];
                     sx_s[tid - 128] = sx[row0 + tid - 128];
                     t_s[tid - 128]  = target[row0 + tid - 128]; }

    const signed char* ga = Xq + (size_t)(row0 + wave*32 + (lane >> 2)) * DIM + (lane & 3) * 16;
    const signed char* gb = Wq + (size_t)(col0 + wave*32 + (lane >> 2)) * DIM + (lane & 3) * 16;
    signed char* la0 = &Als[(wave*32     ) * 64];
    signed char* la1 = &Als[(wave*32 + 16) * 64];
    signed char* lb0 = &Bls[(wave*32     ) * 64];
    signed char* lb1 = &Bls[(wave*32 + 16) * 64];

    const int q = lane >> 4, c = lane & 15;     // quad, col-in-16
    const int wm = wave >> 1, wn = wave & 1;
    const signed char* ap = &Als[(wm*64 + c) * 64 + q * 16];
    const signed char* bp = &Bls[(wn*64 + c) * 64 + q * 16];

    i32x4 acc[4][4];
    #pragma unroll
    for (int i = 0; i < 4; i++)
        #pragma unroll
        for (int j = 0; j < 4; j++) acc[i][j] = (i32x4){0, 0, 0, 0};

    for (int k0 = 0; k0 < DIM; k0 += 64) {
        __builtin_amdgcn_global_load_lds((const GLOBAL_AS void*)(ga + k0),           (LDS_AS void*)la0, 16, 0, 0);
        __builtin_amdgcn_global_load_lds((const GLOBAL_AS void*)(ga + 16*DIM + k0),  (LDS_AS void*)la1, 16, 0, 0);
        __builtin_amdgcn_global_load_lds((const GLOBAL_AS void*)(gb + k0),           (LDS_AS void*)lb0, 16, 0, 0);
        __builtin_amdgcn_global_load_lds((const GLOBAL_AS void*)(gb + 16*DIM + k0),  (LDS_AS void*)lb1, 16, 0, 0);
        __syncthreads();
        i32x4 af[4], bfr[4];
        #pragma unroll
        for (int i = 0; i < 4; i++) af[i]  = *(const i32x4*)(ap + i * 16 * 64);
        #pragma unroll
        for (int j = 0; j < 4; j++) bfr[j] = *(const i32x4*)(bp + j * 16 * 64);
        #pragma unroll
        for (int i = 0; i < 4; i++)
            #pragma unroll
            for (int j = 0; j < 4; j++)
                acc[i][j] = __builtin_amdgcn_mfma_i32_16x16x64_i8(af[i], bfr[j], acc[i][j], 0, 0, 0);
        __syncthreads();
    }

    // epilogue: banded compare-count. C/D: col=lane&15, row=q*4+reg (dtype-independent).
    #pragma unroll
    for (int i = 0; i < 4; i++) {
        #pragma unroll
        for (int reg = 0; reg < 4; reg++) {
            int r = wm*64 + i*16 + q*4 + reg;
            float stv = st_s[r];
            float sxr = sx_s[r];
            int   t   = t_s[r];
            int def = 0, unc = 0;
            #pragma unroll
            for (int j = 0; j < 4; j++) {
                int col_l = wn*64 + j*16 + c;
                float dot = sxr * sw_s[col_l] * (float)acc[i][j][reg];
                float s = w2_s[col_l] - 2.0f * dot;
                int v = col0 + col_l;                 // pad cols: w2=1e30 -> never counted
                if (v != t) {
                    if      (s < stv - MARGIN) def++;
                    else if (s < stv + MARGIN) unc++;
                }
            }
            int pk = (def << 16) | unc;               // per-block <=128 each: fits
            pk += __shfl_xor(pk, 1, 64);
            pk += __shfl_xor(pk, 2, 64);
            pk += __shfl_xor(pk, 4, 64);
            pk += __shfl_xor(pk, 8, 64);
            if (c == 0) atomicAdd(&pk_s[r], pk);
        }
    }
    __syncthreads();
    if (tid < 128) {
        int pk = pk_s[tid];
        if (pk) {
            atomicAdd(&cnt_def[row0 + tid], pk >> 16);
            atomicAdd(&cnt_unc[row0 + tid], pk & 0xffff);
        }
    }
}

// ---------------- resolve: definite rows -> hit, ambiguous -> list ----------------
__global__ __launch_bounds__(256) void resolve_kernel(const int* __restrict__ cnt_def,
                                                      const int* __restrict__ cnt_unc,
                                                      int* __restrict__ hit,
                                                      int* __restrict__ count_exact,
                                                      int* __restrict__ amb_rows,
                                                      int* __restrict__ amb_count) {
    int n = blockIdx.x * 256 + threadIdx.x;
    if (n >= N_ROWS) return;
    int d = cnt_def[n], u = cnt_unc[n];
    int h;
    if (d >= TOPK) h = 0;
    else if (d + u < TOPK) h = 1;
    else {
        h = 2;
        count_exact[n] = d;
        int idx = atomicAdd(amb_count, 1);
        amb_rows[idx] = n;
    }
    hit[n] = h;
}

// ---------------- i8 band rescan over Wq (ambiguous rows only) ----------------
// Wave per word: lane owns 8 bytes of K (coalesced 512 B/wave), exact int dot
// reproduces the GEMM's acc bitwise; float s-expression replicated verbatim,
// so band membership is identical to the GEMM's unc classification.
__device__ __forceinline__ int dot4i8(int a, int b, int acc) {
#if __has_builtin(__builtin_amdgcn_sdot4)
    return __builtin_amdgcn_sdot4(a, b, acc, false);
#else
    #pragma unroll
    for (int j = 0; j < 4; j++)
        acc += (int)(signed char)(a >> (8*j)) * (int)(signed char)(b >> (8*j));
    return acc;
#endif
}

__global__ __launch_bounds__(256) void band_rescan(
        const signed char* __restrict__ Xq, const signed char* __restrict__ Wq,
        const float* __restrict__ sx, const float* __restrict__ sw,
        const float* __restrict__ w2, const float* __restrict__ st,
        const int* __restrict__ target,
        const int* __restrict__ amb_rows, const int* __restrict__ amb_count,
        int* __restrict__ band_n, unsigned int* __restrict__ pairs,
        int* __restrict__ pair_count,
        int* __restrict__ full_rows, int* __restrict__ full_count,
        int* __restrict__ ov) {
    const int wave = threadIdx.x >> 6, lane = threadIdx.x & 63;
    const long ntask = (long)amb_count[0] * VPAD;
    for (long idx = (long)blockIdx.x * 4 + wave; idx < ntask; idx += (long)gridDim.x * 4) {
        const int row = amb_rows[(int)(idx / VPAD)];
        const int v   = (int)(idx % VPAD);
        int2 xa = *(const int2*)(Xq + (size_t)row * DIM + lane * 8);
        int2 wa = *(const int2*)(Wq + (size_t)v   * DIM + lane * 8);
        int acc = dot4i8(xa.x, wa.x, 0);
        acc = dot4i8(xa.y, wa.y, acc);
        acc += __shfl_xor(acc, 1, 64);
        acc += __shfl_xor(acc, 2, 64);
        acc += __shfl_xor(acc, 4, 64);
        acc += __shfl_xor(acc, 8, 64);
        acc += __shfl_xor(acc, 16, 64);
        acc += __shfl_xor(acc, 32, 64);
        if (lane == 0 && v != target[row]) {
            // EXACT replica of the GEMM epilogue's float sequence:
            float dot = sx[row] * sw[v] * (float)acc;
            float s = w2[v] - 2.0f * dot;
            float stv = st[row];
            if (!(s < stv - MARGIN) && (s < stv + MARGIN)) {
                int pos = atomicAdd(&band_n[row], 1);
                if (pos < MAXB) {
                    int slot = atomicAdd(pair_count, 1);
                    pairs[slot] = ((unsigned)row << 16) | (unsigned)v;
                } else if (pos == MAXB) {       // first overflow: flag row for full scan
                    int fslot = atomicAdd(full_count, 1);
                    full_rows[fslot] = row;
                    ov[row] = 1;
                }
            }
        }
    }
}

// ---------------- exact fp32 check of band pairs (wave per pair) ----------------
__global__ __launch_bounds__(256) void exact_pairs(const float* __restrict__ X,
                                                   const float* __restrict__ W,
                                                   const float* __restrict__ w2,
                                                   const float* __restrict__ st,
                                                   const int* __restrict__ target,
                                                   const unsigned int* __restrict__ pairs,
                                                   const int* __restrict__ pair_count,
                                                   int* __restrict__ count_exact) {
    const int wave = threadIdx.x >> 6, lane = threadIdx.x & 63;
    const int np = pair_count[0];
    for (int p = blockIdx.x * 4 + wave; p < np; p += gridDim.x * 4) {
        unsigned pk = pairs[p];
        int row = pk >> 16, v = pk & 0xffff;
        const float4* xr = (const float4*)(X + (size_t)row * DIM + lane * 8);
        const float4* wr = (const float4*)(W + (size_t)v   * DIM + lane * 8);
        float4 xa = xr[0], xb = xr[1];
        float4 wa = wr[0], wb = wr[1];
        float pdot = xa.x*wa.x + xa.y*wa.y + xa.z*wa.z + xa.w*wa.w
                   + xb.x*wb.x + xb.y*wb.y + xb.z*wb.z + xb.w*wb.w;
        pdot += __shfl_xor(pdot, 1, 64);
        pdot += __shfl_xor(pdot, 2, 64);
        pdot += __shfl_xor(pdot, 4, 64);
        pdot += __shfl_xor(pdot, 8, 64);
        pdot += __shfl_xor(pdot, 16, 64);
        pdot += __shfl_xor(pdot, 32, 64);
        if (lane == 0) {
            float s = w2[v] - 2.0f * pdot;
            float stv = st[row];
            int t = target[row];
            if (s < stv || (s == stv && v < t)) atomicAdd(&count_exact[row], 1);
        }
    }
}

// ---------------- full exact rescan (band-overflow rows only; normally 0) ----------------
__global__ __launch_bounds__(256) void exact_kernel(const float* __restrict__ X,
                                                    const float* __restrict__ W,
                                                    const float* __restrict__ w2,
                                                    const float* __restrict__ st,
                                                    const int* __restrict__ target,
                                                    const int* __restrict__ full_rows,
                                                    const int* __restrict__ full_count,
                                                    int* __restrict__ count_full) {
    __shared__ float xs[DIM];
    __shared__ int scnt[4];
    const int tid = threadIdx.x, wave = tid >> 6, lane = tid & 63;
    const int nw = full_count[0] * ECHUNKS;
    for (int w = blockIdx.x; w < nw; w += gridDim.x) {
        const int row   = full_rows[w / ECHUNKS];
        const int chunk = w % ECHUNKS;
        __syncthreads();
        for (int i = tid; i < DIM; i += 256) xs[i] = X[(size_t)row * DIM + i];
        if (tid < 4) scnt[tid] = 0;
        __syncthreads();
        const float4 xa = *(const float4*)&xs[lane * 8];
        const float4 xb = *(const float4*)&xs[lane * 8 + 4];
        const float stv = st[row];
        const int   t   = target[row];
        int cnt = 0;
        const int v0 = chunk * 256 + wave * 64;
        #pragma unroll 2
        for (int i = 0; i < 64; i++) {
            int v = v0 + i;
            if (v < VOCAB) {
                const float4* wr = (const float4*)(W + (size_t)v * DIM + lane * 8);
                float4 wa = wr[0], wb = wr[1];
                float p = xa.x*wa.x + xa.y*wa.y + xa.z*wa.z + xa.w*wa.w
                        + xb.x*wb.x + xb.y*wb.y + xb.z*wb.z + xb.w*wb.w;
                p += __shfl_xor(p, 1, 64);
                p += __shfl_xor(p, 2, 64);
                p += __shfl_xor(p, 4, 64);
                p += __shfl_xor(p, 8, 64);
                p += __shfl_xor(p, 16, 64);
                p += __shfl_xor(p, 32, 64);
                float s = w2[v] - 2.0f * p;
                if (lane == 0 && v != t && (s < stv || (s == stv && v < t))) cnt++;
            }
        }
        if (lane == 0) scnt[wave] = cnt;
        __syncthreads();
        if (tid == 0)
            atomicAdd(&count_full[row], scnt[0] + scnt[1] + scnt[2] + scnt[3]);
    }
}

// ---------------- final reduction ----------------
__global__ __launch_bounds__(256) void finalize2(const int* __restrict__ hit,
                                                 const int* __restrict__ count_exact,
                                                 const int* __restrict__ count_full,
                                                 const int* __restrict__ ov,
                                                 const int* __restrict__ mask,
                                                 float* __restrict__ out) {
    int tid = threadIdx.x;
    int hits = 0, msum = 0;
    for (int n = tid; n < N_ROWS; n += 256) {
        int m = mask[n];
        msum += m;
        int h = hit[n];
        int hv;
        if (h < 2) hv = h;
        else if (ov[n]) hv = (count_full[n] < TOPK) ? 1 : 0;
        else hv = (count_exact[n] < TOPK) ? 1 : 0;
        if (m) hits += hv;
    }
    #pragma unroll
    for (int off = 32; off > 0; off >>= 1) {
        hits += __shfl_down(hits, off, 64);
        msum += __shfl_down(msum, off, 64);
    }
    __shared__ int sh[8];
    int wid = tid >> 6, lane = tid & 63;
    if (lane == 0) { sh[wid] = hits; sh[4 + wid] = msum; }
    __syncthreads();
    if (tid == 0) {
        int H = sh[0] + sh[1] + sh[2] + sh[3];
        int M = sh[4] + sh[5] + sh[6] + sh[7];
        out[0] = (float)H / (float)M;
    }
}

// ================= round-1 verified fp32 fallback (if ws too small) =================
#define BM 128
#define BN 128
#define BK 16
#define TM 8
#define TN 8

__global__ __launch_bounds__(64) void w2_kernel_fb(const float* __restrict__ W,
                                                   float* __restrict__ w2) {
    int v = blockIdx.x;
    const float4* w4 = (const float4*)(W + (size_t)v * DIM);
    int lane = threadIdx.x;
    float4 a = w4[lane];
    float4 b = w4[lane + 64];
    float s = a.x*a.x + a.y*a.y + a.z*a.z + a.w*a.w
            + b.x*b.x + b.y*b.y + b.z*b.z + b.w*b.w;
    #pragma unroll
    for (int off = 32; off > 0; off >>= 1) s += __shfl_down(s, off, 64);
    if (lane == 0) w2[v] = s;
}

__global__ __launch_bounds__(256) void count_kernel_fb(
        const float* __restrict__ X, const float* __restrict__ W,
        const float* __restrict__ w2, const float* __restrict__ st,
        const int* __restrict__ target, int* __restrict__ count) {
    __shared__ float Xs[BK][BM];
    __shared__ float Ws[BK][BN];
    __shared__ float st_s[BM];
    __shared__ int   t_s[BM];
    __shared__ float w2_s[BN];
    const int tid  = threadIdx.x;
    const int row0 = blockIdx.y * BM;
    const int col0 = blockIdx.x * BN;
    if (tid < 128) { st_s[tid] = st[row0 + tid]; t_s[tid] = target[row0 + tid]; }
    else { int cc = tid - 128; int v = col0 + cc; if (v >= VOCAB) v = VOCAB - 1; w2_s[cc] = w2[v]; }
    float acc[TM][TN] = {};
    const int tx = tid & 15;
    const int ty = tid >> 4;
    for (int k0 = 0; k0 < DIM; k0 += BK) {
        #pragma unroll
        for (int j = 0; j < 2; j++) {
            int idx = tid + 256 * j;
            int r   = idx >> 2;
            int kq  = idx & 3;
            float4 xv = *(const float4*)(X + (size_t)(row0 + r) * DIM + k0 + kq * 4);
            Xs[kq*4+0][r] = xv.x; Xs[kq*4+1][r] = xv.y;
            Xs[kq*4+2][r] = xv.z; Xs[kq*4+3][r] = xv.w;
            int v = col0 + r; if (v >= VOCAB) v = VOCAB - 1;
            float4 wv = *(const float4*)(W + (size_t)v * DIM + k0 + kq * 4);
            Ws[kq*4+0][r] = wv.x; Ws[kq*4+1][r] = wv.y;
            Ws[kq*4+2][r] = wv.z; Ws[kq*4+3][r] = wv.w;
        }
        __syncthreads();
        #pragma unroll
        for (int kk = 0; kk < BK; kk++) {
            float a[TM], b[TN];
            #pragma unroll
            for (int i = 0; i < TM; i++) a[i] = Xs[kk][ty * TM + i];
            #pragma unroll
            for (int j = 0; j < TN; j++) b[j] = Ws[kk][tx * TN + j];
            #pragma unroll
            for (int i = 0; i < TM; i++)
                #pragma unroll
                for (int j = 0; j < TN; j++)
                    acc[i][j] += a[i] * b[j];
        }
        __syncthreads();
    }
    int cnt[TM];
    #pragma unroll
    for (int i = 0; i < TM; i++) {
        cnt[i] = 0;
        float stv = st_s[ty * TM + i];
        int   t   = t_s[ty * TM + i];
        #pragma unroll
        for (int j = 0; j < TN; j++) {
            int v = col0 + tx * TN + j;
            float s = w2_s[tx * TN + j] - 2.0f * acc[i][j];
            if (v < VOCAB && v != t && (s < stv || (s == stv && v < t))) cnt[i]++;
        }
    }
    __syncthreads();
    int* scnt = (int*)Xs;
    #pragma unroll
    for (int i = 0; i < TM; i++) scnt[(ty * TM + i) * 16 + tx] = cnt[i];
    __syncthreads();
    if (tid < BM) {
        int s = 0;
        #pragma unroll
        for (int j = 0; j < 16; j++) s += scnt[tid * 16 + j];
        atomicAdd(&count[row0 + tid], s);
    }
}

__global__ __launch_bounds__(256) void finalize_fb(const int* __restrict__ count,
                                                   const int* __restrict__ mask,
                                                   float* __restrict__ out) {
    int tid = threadIdx.x;
    int hits = 0, msum = 0;
    for (int n = tid; n < N_ROWS; n += 256) {
        int m = mask[n];
        msum += m;
        if (m && count[n] < TOPK) hits++;
    }
    #pragma unroll
    for (int off = 32; off > 0; off >>= 1) {
        hits += __shfl_down(hits, off, 64);
        msum += __shfl_down(msum, off, 64);
    }
    __shared__ int sh[8];
    int wid = tid >> 6, lane = tid & 63;
    if (lane == 0) { sh[wid] = hits; sh[4 + wid] = msum; }
    __syncthreads();
    if (tid == 0) {
        int H = sh[0] + sh[1] + sh[2] + sh[3];
        int M = sh[4] + sh[5] + sh[6] + sh[7];
        out[0] = (float)H / (float)M;
    }
}

// ================= launch =================
extern "C" void kernel_launch(void* const* d_in, const int* in_sizes, int n_in,
                              void* d_out, int out_size, void* d_ws, size_t ws_size,
                              hipStream_t stream) {
    const float* X      = (const float*)d_in[0];
    const int*   target = (const int*)d_in[1];
    const int*   mask   = (const int*)d_in[2];
    const float* W      = (const float*)d_in[3];
    float* out = (float*)d_out;
    char* ws = (char*)d_ws;

    const size_t oXq   = 0;
    const size_t oWq   = oXq  + (size_t)N_ROWS * DIM;       //  2,097,152
    const size_t osx   = oWq  + (size_t)VPAD  * DIM;        // 27,721,728
    const size_t osw   = osx  + (size_t)N_ROWS * 4;
    const size_t ow2   = osw  + (size_t)VPAD * 4;
    const size_t ost   = ow2  + (size_t)VPAD * 4;
    const size_t ocd   = ost  + (size_t)N_ROWS * 4;         // zeroed region starts here
    const size_t ocu   = ocd  + (size_t)N_ROWS * 4;
    const size_t oce   = ocu  + (size_t)N_ROWS * 4;
    const size_t ocf   = oce  + (size_t)N_ROWS * 4;
    const size_t oov   = ocf  + (size_t)N_ROWS * 4;
    const size_t obn   = oov  + (size_t)N_ROWS * 4;
    const size_t ohit  = obn  + (size_t)N_ROWS * 4;
    const size_t oamb  = ohit + (size_t)N_ROWS * 4;
    const size_t ofr   = oamb + (size_t)N_ROWS * 4;
    const size_t octr  = ofr  + (size_t)N_ROWS * 4;          // amb_count|pair_count|full_count
    const size_t oprs  = octr + 64;                          // end of zeroed region
    const size_t need  = oprs + (size_t)N_ROWS * MAXB * 4;   // pairs 1 MB

    if (ws_size >= need) {
        signed char* Xq = (signed char*)(ws + oXq);
        signed char* Wq = (signed char*)(ws + oWq);
        float* sx = (float*)(ws + osx);
        float* sw = (float*)(ws + osw);
        float* w2 = (float*)(ws + ow2);
        float* st = (float*)(ws + ost);
        int* cnt_def = (int*)(ws + ocd);
        int* cnt_unc = (int*)(ws + ocu);
        int* count_exact = (int*)(ws + oce);
        int* count_full = (int*)(ws + ocf);
        int* ov = (int*)(ws + oov);
        int* band_n = (int*)(ws + obn);
        int* hit = (int*)(ws + ohit);
        int* amb_rows = (int*)(ws + oamb);
        int* full_rows = (int*)(ws + ofr);
        int* amb_count  = (int*)(ws + octr);
        int* pair_count = (int*)(ws + octr + 16);
        int* full_count = (int*)(ws + octr + 32);
        unsigned int* pairs = (unsigned int*)(ws + oprs);

        hipMemsetAsync(ws + ocd, 0, oprs - ocd, stream);
        quantize_x<<<N_ROWS / 4, 256, 0, stream>>>(X, Xq, sx);
        quantize_w<<<VPAD / 4, 256, 0, stream>>>(W, Wq, sw, w2);
        st_kernel<<<N_ROWS, 64, 0, stream>>>(X, W, target, st);
        count_mfma_i8<<<dim3(N_ROWS / 128, VPAD / 128), 256, 0, stream>>>(
            Xq, Wq, sx, sw, w2, st, target, cnt_def, cnt_unc);
        resolve_kernel<<<16, 256, 0, stream>>>(cnt_def, cnt_unc, hit, count_exact,
                                               amb_rows, amb_count);
        band_rescan<<<512, 256, 0, stream>>>(Xq, Wq, sx, sw, w2, st, target,
                                             amb_rows, amb_count, band_n,
                                             pairs, pair_count, full_rows, full_count, ov);
        exact_pairs<<<128, 256, 0, stream>>>(X, W, w2, st, target, pairs, pair_count, count_exact);
        exact_kernel<<<512, 256, 0, stream>>>(X, W, w2, st, target, full_rows, full_count, count_full);
        finalize2<<<1, 256, 0, stream>>>(hit, count_exact, count_full, ov, mask, out);
    } else {
        float* w2 = (float*)ws;
        float* st = (float*)(ws + 200704);
        int* countp = (int*)(ws + 200704 + 16384);
        hipMemsetAsync(countp, 0, N_ROWS * sizeof(int), stream);
        w2_kernel_fb<<<VOCAB, 64, 0, stream>>>(W, w2);
        st_kernel<<<N_ROWS, 64, 0, stream>>>(X, W, target, st);
        dim3 grid((VOCAB + BN - 1) / BN, N_ROWS / BM);
        count_kernel_fb<<<grid, 256, 0, stream>>>(X, W, w2, st, target, countp);
        finalize_fb<<<1, 256, 0, stream>>>(countp, mask, out);
    }
}

// Round 7
// 416.415 us; speedup vs baseline: 6.9906x; 1.0894x over previous
//
#include <hip/hip_runtime.h>
#include <stdint.h>

#define N_ROWS 4096
#define DIM    512
#define VOCAB  50000
#define VPAD   50048
#define TOPK   10
#define MARGIN 8.0f            // i8 band: >=13 sigma of quantization error

typedef int i32x4 __attribute__((ext_vector_type(4)));

#define GLOBAL_AS __attribute__((address_space(1)))
#define LDS_AS    __attribute__((address_space(3)))

// ---------------- per-row int8 quantization (wave per row) ----------------
__device__ __forceinline__ void quant_row(const float* __restrict__ src,
                                          signed char* __restrict__ dst,
                                          int lane, float* rowmax_out,
                                          float* w2_out) {
    const float4* s4 = (const float4*)(src + lane * 8);
    float4 a = s4[0], b = s4[1];
    float mx = fmaxf(fmaxf(fmaxf(fabsf(a.x), fabsf(a.y)), fmaxf(fabsf(a.z), fabsf(a.w))),
                     fmaxf(fmaxf(fabsf(b.x), fabsf(b.y)), fmaxf(fabsf(b.z), fabsf(b.w))));
    float w2 = a.x*a.x + a.y*a.y + a.z*a.z + a.w*a.w
             + b.x*b.x + b.y*b.y + b.z*b.z + b.w*b.w;
    #pragma unroll
    for (int off = 1; off < 64; off <<= 1) {
        mx  = fmaxf(mx, __shfl_xor(mx, off, 64));
        w2 += __shfl_xor(w2, off, 64);
    }
    float inv = 127.0f / fmaxf(mx, 1e-30f);
    int q0 = (int)rintf(a.x * inv), q1 = (int)rintf(a.y * inv);
    int q2 = (int)rintf(a.z * inv), q3 = (int)rintf(a.w * inv);
    int q4 = (int)rintf(b.x * inv), q5 = (int)rintf(b.y * inv);
    int q6 = (int)rintf(b.z * inv), q7 = (int)rintf(b.w * inv);
    uint2 pk;
    pk.x = (q0 & 0xff) | ((q1 & 0xff) << 8) | ((q2 & 0xff) << 16) | ((unsigned)(q3 & 0xff) << 24);
    pk.y = (q4 & 0xff) | ((q5 & 0xff) << 8) | ((q6 & 0xff) << 16) | ((unsigned)(q7 & 0xff) << 24);
    *(uint2*)(dst + lane * 8) = pk;
    *rowmax_out = mx;
    *w2_out = w2;
}

// ---------------- fused prep: zero counters + quantize X + quantize W + st ----------------
#define PREP_Z  64                              // zeroing blocks
#define PREP_QX (PREP_Z + N_ROWS / 4)           // 1088
#define PREP_QW (PREP_QX + VPAD / 4)            // 13600
#define PREP_ST (PREP_QW + N_ROWS / 4)          // 14624 total blocks

__global__ __launch_bounds__(256) void prep_kernel(
        const float* __restrict__ X, const float* __restrict__ W,
        const int* __restrict__ target,
        signed char* __restrict__ Xq, signed char* __restrict__ Wq,
        float* __restrict__ sx, float* __restrict__ sw,
        float* __restrict__ w2, float* __restrict__ st,
        int* __restrict__ zbase) {
    const int b = blockIdx.x;
    const int wave = threadIdx.x >> 6, lane = threadIdx.x & 63;
    if (b < PREP_Z) {
        int i = b * 256 + threadIdx.x;
        if (i < 3 * N_ROWS + 16) zbase[i] = 0;     // cnt_def | cnt_unc | count_exact | ctrs
    } else if (b < PREP_QX) {
        int row = (b - PREP_Z) * 4 + wave;
        float mx, w2v;
        quant_row(X + (size_t)row * DIM, Xq + (size_t)row * DIM, lane, &mx, &w2v);
        if (lane == 0) sx[row] = fmaxf(mx, 1e-30f) / 127.0f;
    } else if (b < PREP_QW) {
        int row = (b - PREP_QX) * 4 + wave;
        if (row < VOCAB) {
            float mx, s2;
            quant_row(W + (size_t)row * DIM, Wq + (size_t)row * DIM, lane, &mx, &s2);
            if (lane == 0) { sw[row] = fmaxf(mx, 1e-30f) / 127.0f; w2[row] = s2; }
        } else {
            *(uint2*)(Wq + (size_t)row * DIM + lane * 8) = make_uint2(0, 0);
            if (lane == 0) { sw[row] = 0.0f; w2[row] = 1e30f; }
        }
    } else {
        int n = (b - PREP_QW) * 4 + wave;
        int t = target[n];
        const float4* x4 = (const float4*)(X + (size_t)n * DIM);
        const float4* w4 = (const float4*)(W + (size_t)t * DIM);
        float4 xa = x4[lane], xb = x4[lane + 64];
        float4 wa = w4[lane], wb = w4[lane + 64];
        float sxw = xa.x*wa.x + xa.y*wa.y + xa.z*wa.z + xa.w*wa.w
                  + xb.x*wb.x + xb.y*wb.y + xb.z*wb.z + xb.w*wb.w;
        float sww = wa.x*wa.x + wa.y*wa.y + wa.z*wa.z + wa.w*wa.w
                  + wb.x*wb.x + wb.y*wb.y + wb.z*wb.z + wb.w*wb.w;
        #pragma unroll
        for (int off = 32; off > 0; off >>= 1) {
            sxw += __shfl_down(sxw, off, 64);
            sww += __shfl_down(sww, off, 64);
        }
        if (lane == 0) st[n] = sww - 2.0f * sxw;
    }
}

// ---------------- i8 MFMA GEMM + band-count (round-4 structure + LDS XOR swizzle) ----------------
// 128x128 tile, BK=64 bytes, 4 waves (2x2), mfma_i32_16x16x64_i8, 4x4 frags/wave.
// LDS chunk swizzle: LDS[r][slot] = G[r][slot ^ ((r>>1)&3)]. Staging permutes the
// GLOBAL source chunk per lane (glds dest stays lane-contiguous); readers XOR back.
__global__ __launch_bounds__(256) void count_mfma_i8(
        const signed char* __restrict__ Xq, const signed char* __restrict__ Wq,
        const float* __restrict__ sx, const float* __restrict__ sw,
        const float* __restrict__ w2, const float* __restrict__ st,
        const int* __restrict__ target,
        int* __restrict__ cnt_def, int* __restrict__ cnt_unc) {

    __shared__ signed char Als[128 * 64];
    __shared__ signed char Bls[128 * 64];
    __shared__ float w2_s[128];
    __shared__ float sw_s[128];
    __shared__ float st_s[128];
    __shared__ float sx_s[128];
    __shared__ int   t_s[128];
    __shared__ int   pk_s[128];

    const int tid  = threadIdx.x;
    const int wave = tid >> 6, lane = tid & 63;
    const int row0 = blockIdx.x * 128;          // x fastest -> W-tile reuse across 32 blocks
    const int col0 = blockIdx.y * 128;

    if (tid < 128) { w2_s[tid] = w2[col0 + tid]; sw_s[tid] = sw[col0 + tid]; pk_s[tid] = 0; }
    else           { st_s[tid - 128] = st[row0 + tid - 128];
                     sx_s[tid - 128] = sx[row0 + tid - 128];
                     t_s[tid - 128]  = target[row0 + tid - 128]; }

    // staging: lane -> row=lane>>2, LDS slot=lane&3; fetch global chunk (slot ^ f(row)),
    // f(row) = (row>>1)&3 = (lane>>3)&3 within each 16-row group (+16 rows keeps f).
    const int ch = (lane & 3) ^ ((lane >> 3) & 3);
    const signed char* ga = Xq + (size_t)(row0 + wave*32 + (lane >> 2)) * DIM + ch * 16;
    const signed char* gb = Wq + (size_t)(col0 + wave*32 + (lane >> 2)) * DIM + ch * 16;
    signed char* la0 = &Als[(wave*32     ) * 64];
    signed char* la1 = &Als[(wave*32 + 16) * 64];
    signed char* lb0 = &Bls[(wave*32     ) * 64];
    signed char* lb1 = &Bls[(wave*32 + 16) * 64];

    const int q = lane >> 4, c = lane & 15;     // quad, col-in-16
    const int fs = (c >> 1) & 3;                // f(row) for frag rows (wm*64+i*16+c)
    const int wm = wave >> 1, wn = wave & 1;
    const signed char* ap = &Als[(wm*64 + c) * 64 + (q ^ fs) * 16];
    const signed char* bp = &Bls[(wn*64 + c) * 64 + (q ^ fs) * 16];

    i32x4 acc[4][4];
    #pragma unroll
    for (int i = 0; i < 4; i++)
        #pragma unroll
        for (int j = 0; j < 4; j++) acc[i][j] = (i32x4){0, 0, 0, 0};

    for (int k0 = 0; k0 < DIM; k0 += 64) {
        __builtin_amdgcn_global_load_lds((const GLOBAL_AS void*)(ga + k0),           (LDS_AS void*)la0, 16, 0, 0);
        __builtin_amdgcn_global_load_lds((const GLOBAL_AS void*)(ga + 16*DIM + k0),  (LDS_AS void*)la1, 16, 0, 0);
        __builtin_amdgcn_global_load_lds((const GLOBAL_AS void*)(gb + k0),           (LDS_AS void*)lb0, 16, 0, 0);
        __builtin_amdgcn_global_load_lds((const GLOBAL_AS void*)(gb + 16*DIM + k0),  (LDS_AS void*)lb1, 16, 0, 0);
        __syncthreads();
        i32x4 af[4], bfr[4];
        #pragma unroll
        for (int i = 0; i < 4; i++) af[i]  = *(const i32x4*)(ap + i * 16 * 64);
        #pragma unroll
        for (int j = 0; j < 4; j++) bfr[j] = *(const i32x4*)(bp + j * 16 * 64);
        #pragma unroll
        for (int i = 0; i < 4; i++)
            #pragma unroll
            for (int j = 0; j < 4; j++)
                acc[i][j] = __builtin_amdgcn_mfma_i32_16x16x64_i8(af[i], bfr[j], acc[i][j], 0, 0, 0);
        __syncthreads();
    }

    // epilogue: banded compare-count. C/D: col=lane&15, row=q*4+reg (dtype-independent).
    #pragma unroll
    for (int i = 0; i < 4; i++) {
        #pragma unroll
        for (int reg = 0; reg < 4; reg++) {
            int r = wm*64 + i*16 + q*4 + reg;
            float stv = st_s[r];
            float sxr = sx_s[r];
            int   t   = t_s[r];
            int def = 0, unc = 0;
            #pragma unroll
            for (int j = 0; j < 4; j++) {
                int col_l = wn*64 + j*16 + c;
                float dot = sxr * sw_s[col_l] * (float)acc[i][j][reg];
                float s = w2_s[col_l] - 2.0f * dot;
                int v = col0 + col_l;                 // pad cols: w2=1e30 -> never counted
                if (v != t) {
                    if      (s < stv - MARGIN) def++;
                    else if (s < stv + MARGIN) unc++;
                }
            }
            int pk = (def << 16) | unc;               // per-block <=128 each: fits
            pk += __shfl_xor(pk, 1, 64);
            pk += __shfl_xor(pk, 2, 64);
            pk += __shfl_xor(pk, 4, 64);
            pk += __shfl_xor(pk, 8, 64);
            if (c == 0) atomicAdd(&pk_s[r], pk);
        }
    }
    __syncthreads();
    if (tid < 128) {
        int pk = pk_s[tid];
        if (pk) {
            atomicAdd(&cnt_def[row0 + tid], pk >> 16);
            atomicAdd(&cnt_unc[row0 + tid], pk & 0xffff);
        }
    }
}

// ---------------- resolve: build ambiguous-row list ----------------
__global__ __launch_bounds__(256) void resolve3(const int* __restrict__ cnt_def,
                                                const int* __restrict__ cnt_unc,
                                                int* __restrict__ amb_rows,
                                                int* __restrict__ amb_count) {
    int n = blockIdx.x * 256 + threadIdx.x;
    if (n >= N_ROWS) return;
    int d = cnt_def[n], u = cnt_unc[n];
    if (d < TOPK && d + u >= TOPK) {
        int idx = atomicAdd(amb_count, 1);
        amb_rows[idx] = n;
    }
}

// ---------------- band scan: i8 re-dot + inline exact fp32 verify ----------------
// Wave per word (lane owns 8 bytes of K, coalesced). The i8 int dot reproduces the
// GEMM's acc exactly (integer, order-free); the float s-expression is replicated
// verbatim, so band classification is bitwise-identical to the GEMM epilogue.
// Band members (wave-uniform predicate: acc is uniform after butterfly) get an
// immediate inline fp32 exact dot -> atomicAdd(count_exact). No capacity limits.
__device__ __forceinline__ int dot4i8(int a, int b, int acc) {
#if __has_builtin(__builtin_amdgcn_sdot4)
    return __builtin_amdgcn_sdot4(a, b, acc, false);
#else
    #pragma unroll
    for (int j = 0; j < 4; j++)
        acc += (int)(signed char)(a >> (8*j)) * (int)(signed char)(b >> (8*j));
    return acc;
#endif
}

__global__ __launch_bounds__(256) void band_scan(
        const signed char* __restrict__ Xq, const signed char* __restrict__ Wq,
        const float* __restrict__ X, const float* __restrict__ W,
        const float* __restrict__ sx, const float* __restrict__ sw,
        const float* __restrict__ w2, const float* __restrict__ st,
        const int* __restrict__ target,
        const int* __restrict__ amb_rows, const int* __restrict__ amb_count,
        int* __restrict__ count_exact) {
    const int lane = threadIdx.x & 63;
    const int wid  = (blockIdx.x << 2) | (threadIdx.x >> 6);
    const int nw   = gridDim.x << 2;
    const int namb = amb_count[0];
    for (int a = 0; a < namb; a++) {
        const int row = amb_rows[a];
        const int t   = target[row];
        const float sxr = sx[row], stv = st[row];
        const int2 xa8 = *(const int2*)(Xq + (size_t)row * DIM + lane * 8);
        for (int v = wid; v < VPAD; v += nw) {
            int2 wa8 = *(const int2*)(Wq + (size_t)v * DIM + lane * 8);
            int acc = dot4i8(xa8.x, wa8.x, 0);
            acc = dot4i8(xa8.y, wa8.y, acc);
            acc += __shfl_xor(acc, 1, 64);
            acc += __shfl_xor(acc, 2, 64);
            acc += __shfl_xor(acc, 4, 64);
            acc += __shfl_xor(acc, 8, 64);
            acc += __shfl_xor(acc, 16, 64);
            acc += __shfl_xor(acc, 32, 64);
            if (v == t) continue;
            // EXACT replica of the GEMM epilogue float sequence:
            float dot = sxr * sw[v] * (float)acc;
            float s = w2[v] - 2.0f * dot;
            if (!(s < stv - MARGIN) && (s < stv + MARGIN)) {
                const float4* xr = (const float4*)(X + (size_t)row * DIM + lane * 8);
                const float4* wr = (const float4*)(W + (size_t)v   * DIM + lane * 8);
                float4 x0 = xr[0], x1 = xr[1];
                float4 w0 = wr[0], w1 = wr[1];
                float p = x0.x*w0.x + x0.y*w0.y + x0.z*w0.z + x0.w*w0.w
                        + x1.x*w1.x + x1.y*w1.y + x1.z*w1.z + x1.w*w1.w;
                p += __shfl_xor(p, 1, 64);
                p += __shfl_xor(p, 2, 64);
                p += __shfl_xor(p, 4, 64);
                p += __shfl_xor(p, 8, 64);
                p += __shfl_xor(p, 16, 64);
                p += __shfl_xor(p, 32, 64);
                if (lane == 0) {
                    float se = w2[v] - 2.0f * p;
                    if (se < stv || (se == stv && v < t)) atomicAdd(&count_exact[row], 1);
                }
            }
        }
    }
}

// ---------------- final reduction ----------------
__global__ __launch_bounds__(256) void finalize3(const int* __restrict__ cnt_def,
                                                 const int* __restrict__ cnt_unc,
                                                 const int* __restrict__ count_exact,
                                                 const int* __restrict__ mask,
                                                 float* __restrict__ out) {
    int tid = threadIdx.x;
    int hits = 0, msum = 0;
    for (int n = tid; n < N_ROWS; n += 256) {
        int m = mask[n];
        msum += m;
        int d = cnt_def[n], u = cnt_unc[n];
        int hv;
        if (d >= TOPK) hv = 0;
        else if (d + u < TOPK) hv = 1;
        else hv = (d + count_exact[n] < TOPK) ? 1 : 0;
        if (m) hits += hv;
    }
    #pragma unroll
    for (int off = 32; off > 0; off >>= 1) {
        hits += __shfl_down(hits, off, 64);
        msum += __shfl_down(msum, off, 64);
    }
    __shared__ int sh[8];
    int wid = tid >> 6, lane = tid & 63;
    if (lane == 0) { sh[wid] = hits; sh[4 + wid] = msum; }
    __syncthreads();
    if (tid == 0) {
        int H = sh[0] + sh[1] + sh[2] + sh[3];
        int M = sh[4] + sh[5] + sh[6] + sh[7];
        out[0] = (float)H / (float)M;
    }
}

// ================= round-1 verified fp32 fallback (if ws too small) =================
#define BM 128
#define BN 128
#define BK 16
#define TM 8
#define TN 8

__global__ __launch_bounds__(64) void w2_kernel_fb(const float* __restrict__ W,
                                                   float* __restrict__ w2) {
    int v = blockIdx.x;
    const float4* w4 = (const float4*)(W + (size_t)v * DIM);
    int lane = threadIdx.x;
    float4 a = w4[lane];
    float4 b = w4[lane + 64];
    float s = a.x*a.x + a.y*a.y + a.z*a.z + a.w*a.w
            + b.x*b.x + b.y*b.y + b.z*b.z + b.w*b.w;
    #pragma unroll
    for (int off = 32; off > 0; off >>= 1) s += __shfl_down(s, off, 64);
    if (lane == 0) w2[v] = s;
}

__global__ __launch_bounds__(64) void st_kernel_fb(const float* __restrict__ X,
                                                   const float* __restrict__ W,
                                                   const int* __restrict__ target,
                                                   float* __restrict__ st) {
    int n = blockIdx.x;
    int t = target[n];
    const float4* x4 = (const float4*)(X + (size_t)n * DIM);
    const float4* w4 = (const float4*)(W + (size_t)t * DIM);
    int lane = threadIdx.x;
    float4 xa = x4[lane], xb = x4[lane + 64];
    float4 wa = w4[lane], wb = w4[lane + 64];
    float sxw = xa.x*wa.x + xa.y*wa.y + xa.z*wa.z + xa.w*wa.w
              + xb.x*wb.x + xb.y*wb.y + xb.z*wb.z + xb.w*wb.w;
    float sww = wa.x*wa.x + wa.y*wa.y + wa.z*wa.z + wa.w*wa.w
              + wb.x*wb.x + wb.y*wb.y + wb.z*wb.z + wb.w*wb.w;
    #pragma unroll
    for (int off = 32; off > 0; off >>= 1) {
        sxw += __shfl_down(sxw, off, 64);
        sww += __shfl_down(sww, off, 64);
    }
    if (lane == 0) st[n] = sww - 2.0f * sxw;
}

__global__ __launch_bounds__(256) void count_kernel_fb(
        const float* __restrict__ X, const float* __restrict__ W,
        const float* __restrict__ w2, const float* __restrict__ st,
        const int* __restrict__ target, int* __restrict__ count) {
    __shared__ float Xs[BK][BM];
    __shared__ float Ws[BK][BN];
    __shared__ float st_s[BM];
    __shared__ int   t_s[BM];
    __shared__ float w2_s[BN];
    const int tid  = threadIdx.x;
    const int row0 = blockIdx.y * BM;
    const int col0 = blockIdx.x * BN;
    if (tid < 128) { st_s[tid] = st[row0 + tid]; t_s[tid] = target[row0 + tid]; }
    else { int cc = tid - 128; int v = col0 + cc; if (v >= VOCAB) v = VOCAB - 1; w2_s[cc] = w2[v]; }
    float acc[TM][TN] = {};
    const int tx = tid & 15;
    const int ty = tid >> 4;
    for (int k0 = 0; k0 < DIM; k0 += BK) {
        #pragma unroll
        for (int j = 0; j < 2; j++) {
            int idx = tid + 256 * j;
            int r   = idx >> 2;
            int kq  = idx & 3;
            float4 xv = *(const float4*)(X + (size_t)(row0 + r) * DIM + k0 + kq * 4);
            Xs[kq*4+0][r] = xv.x; Xs[kq*4+1][r] = xv.y;
            Xs[kq*4+2][r] = xv.z; Xs[kq*4+3][r] = xv.w;
            int v = col0 + r; if (v >= VOCAB) v = VOCAB - 1;
            float4 wv = *(const float4*)(W + (size_t)v * DIM + k0 + kq * 4);
            Ws[kq*4+0][r] = wv.x; Ws[kq*4+1][r] = wv.y;
            Ws[kq*4+2][r] = wv.z; Ws[kq*4+3][r] = wv.w;
        }
        __syncthreads();
        #pragma unroll
        for (int kk = 0; kk < BK; kk++) {
            float a[TM], b[TN];
            #pragma unroll
            for (int i = 0; i < TM; i++) a[i] = Xs[kk][ty * TM + i];
            #pragma unroll
            for (int j = 0; j < TN; j++) b[j] = Ws[kk][tx * TN + j];
            #pragma unroll
            for (int i = 0; i < TM; i++)
                #pragma unroll
                for (int j = 0; j < TN; j++)
                    acc[i][j] += a[i] * b[j];
        }
        __syncthreads();
    }
    int cnt[TM];
    #pragma unroll
    for (int i = 0; i < TM; i++) {
        cnt[i] = 0;
        float stv = st_s[ty * TM + i];
        int   t   = t_s[ty * TM + i];
        #pragma unroll
        for (int j = 0; j < TN; j++) {
            int v = col0 + tx * TN + j;
            float s = w2_s[tx * TN + j] - 2.0f * acc[i][j];
            if (v < VOCAB && v != t && (s < stv || (s == stv && v < t))) cnt[i]++;
        }
    }
    __syncthreads();
    int* scnt = (int*)Xs;
    #pragma unroll
    for (int i = 0; i < TM; i++) scnt[(ty * TM + i) * 16 + tx] = cnt[i];
    __syncthreads();
    if (tid < BM) {
        int s = 0;
        #pragma unroll
        for (int j = 0; j < 16; j++) s += scnt[tid * 16 + j];
        atomicAdd(&count[row0 + tid], s);
    }
}

__global__ __launch_bounds__(256) void finalize_fb(const int* __restrict__ count,
                                                   const int* __restrict__ mask,
                                                   float* __restrict__ out) {
    int tid = threadIdx.x;
    int hits = 0, msum = 0;
    for (int n = tid; n < N_ROWS; n += 256) {
        int m = mask[n];
        msum += m;
        if (m && count[n] < TOPK) hits++;
    }
    #pragma unroll
    for (int off = 32; off > 0; off >>= 1) {
        hits += __shfl_down(hits, off, 64);
        msum += __shfl_down(msum, off, 64);
    }
    __shared__ int sh[8];
    int wid = tid >> 6, lane = tid & 63;
    if (lane == 0) { sh[wid] = hits; sh[4 + wid] = msum; }
    __syncthreads();
    if (tid == 0) {
        int H = sh[0] + sh[1] + sh[2] + sh[3];
        int M = sh[4] + sh[5] + sh[6] + sh[7];
        out[0] = (float)H / (float)M;
    }
}

// ================= launch =================
extern "C" void kernel_launch(void* const* d_in, const int* in_sizes, int n_in,
                              void* d_out, int out_size, void* d_ws, size_t ws_size,
                              hipStream_t stream) {
    const float* X      = (const float*)d_in[0];
    const int*   target = (const int*)d_in[1];
    const int*   mask   = (const int*)d_in[2];
    const float* W      = (const float*)d_in[3];
    float* out = (float*)d_out;
    char* ws = (char*)d_ws;

    const size_t oXq  = 0;
    const size_t oWq  = oXq + (size_t)N_ROWS * DIM;        //  2,097,152
    const size_t osx  = oWq + (size_t)VPAD  * DIM;         // 27,721,728
    const size_t osw  = osx + (size_t)N_ROWS * 4;
    const size_t ow2  = osw + (size_t)VPAD * 4;
    const size_t ost  = ow2 + (size_t)VPAD * 4;
    const size_t ocd  = ost + (size_t)N_ROWS * 4;          // zeroed region: cnt_def
    const size_t ocu  = ocd + (size_t)N_ROWS * 4;          //   cnt_unc
    const size_t oce  = ocu + (size_t)N_ROWS * 4;          //   count_exact
    const size_t octr = oce + (size_t)N_ROWS * 4;          //   amb_count + pad (16 ints)
    const size_t oamb = octr + 64;
    const size_t need = oamb + (size_t)N_ROWS * 4;

    if (ws_size >= need) {
        signed char* Xq = (signed char*)(ws + oXq);
        signed char* Wq = (signed char*)(ws + oWq);
        float* sx = (float*)(ws + osx);
        float* sw = (float*)(ws + osw);
        float* w2 = (float*)(ws + ow2);
        float* st = (float*)(ws + ost);
        int* cnt_def = (int*)(ws + ocd);
        int* cnt_unc = (int*)(ws + ocu);
        int* count_exact = (int*)(ws + oce);
        int* amb_count = (int*)(ws + octr);
        int* amb_rows = (int*)(ws + oamb);

        prep_kernel<<<PREP_ST, 256, 0, stream>>>(X, W, target, Xq, Wq, sx, sw, w2, st, cnt_def);
        count_mfma_i8<<<dim3(N_ROWS / 128, VPAD / 128), 256, 0, stream>>>(
            Xq, Wq, sx, sw, w2, st, target, cnt_def, cnt_unc);
        resolve3<<<16, 256, 0, stream>>>(cnt_def, cnt_unc, amb_rows, amb_count);
        band_scan<<<512, 256, 0, stream>>>(Xq, Wq, X, W, sx, sw, w2, st, target,
                                           amb_rows, amb_count, count_exact);
        finalize3<<<1, 256, 0, stream>>>(cnt_def, cnt_unc, count_exact, mask, out);
    } else {
        float* w2 = (float*)ws;
        float* st = (float*)(ws + 200704);
        int* countp = (int*)(ws + 200704 + 16384);
        hipMemsetAsync(countp, 0, N_ROWS * sizeof(int), stream);
        w2_kernel_fb<<<VOCAB, 64, 0, stream>>>(W, w2);
        st_kernel_fb<<<N_ROWS, 64, 0, stream>>>(X, W, target, st);
        dim3 grid((VOCAB + BN - 1) / BN, N_ROWS / BM);
        count_kernel_fb<<<grid, 256, 0, stream>>>(X, W, w2, st, target, countp);
        finalize_fb<<<1, 256, 0, stream>>>(countp, mask, out);
    }
}